// Round 4
// baseline (5154.327 us; speedup 1.0000x reference)
//
#include <hip/hip_runtime.h>
#include <hip/hip_bf16.h>

#define S_N 50000
#define E_N 400000
#define FD 128
#define FM 256
#define FM2 1280
#define CH 40000       // nominal chunk edges; boundaries snapped UP to source bounds
#define CH_MAX 40960   // padded chunk capacity (640 * 64); max overshoot = max count
#define NC 10
#define RCH 10000      // MLP2 row chunk, 5 chunks

// jnp.nan_to_num
__device__ __forceinline__ float n2n(float x) {
  if (x != x) return 0.0f;
  const float M = 3.402823466e38f;
  if (x > M) return M;
  if (x < -M) return -M;
  return x;
}

// ---------------------------------------------------------------------------
// Probe index dtype. flags[1] = 1 if int64 edge_index.
// ---------------------------------------------------------------------------
__global__ void probe_kernel(const void* __restrict__ eidx_raw, int* __restrict__ flags)
{
  if (threadIdx.x != 0 || blockIdx.x != 0) return;
  const long long* e64 = (const long long*)eidx_raw;
  int ok64 = 1;
  for (int i = 0; i < 64; ++i) {
    long long v = e64[i];
    if (v < 0 || v >= S_N) { ok64 = 0; break; }
  }
  flags[1] = ok64;
}

// idx normalize + histogram into hist[] (pre-zeroed)
__global__ __launch_bounds__(256) void idx_kernel(
    const void* __restrict__ eidx, int* __restrict__ src32,
    int* __restrict__ tgt32, const int* __restrict__ flags,
    int* __restrict__ hist)
{
  const int e = blockIdx.x * 256 + threadIdx.x;
  if (e >= E_N) return;
  int s, t;
  if (flags[1]) {
    const long long* p = (const long long*)eidx;
    s = (int)p[e];
    t = (int)p[E_N + e];
  } else {
    const int* p = (const int*)eidx;
    s = p[e];
    t = p[E_N + e];
  }
  src32[e] = s;
  tgt32[e] = t;
  atomicAdd(&hist[s], 1);
}

// single-block exclusive scan: hist[s] (counts) -> rowstart[s]; hist becomes
// a working copy of rowstart (consumed by scatter's tickets).
__global__ __launch_bounds__(256) void scan_kernel(
    int* __restrict__ hist, int* __restrict__ rowstart)
{
  __shared__ int tmp[256];
  __shared__ int sbase;
  const int t = threadIdx.x;
  if (t == 0) sbase = 0;
  __syncthreads();
  for (int tile = 0; tile < S_N; tile += 256) {
    const int idx = tile + t;
    const int v = (idx < S_N) ? hist[idx] : 0;
    tmp[t] = v;
    __syncthreads();
    for (int off = 1; off < 256; off <<= 1) {
      int x = 0;
      if (t >= off) x = tmp[t - off];
      __syncthreads();
      tmp[t] += x;
      __syncthreads();
    }
    const int excl = sbase + tmp[t] - v;
    if (idx < S_N) { rowstart[idx] = excl; hist[idx] = excl; }
    __syncthreads();
    if (t == 0) sbase += tmp[255];
    __syncthreads();
  }
  if (t == 0) rowstart[S_N] = sbase;   // == E_N
}

// chunk boundaries snapped to source boundaries:
// Sb[c] = min s with rowstart[s] >= c*CH ; B[c] = rowstart[Sb[c]]
__global__ void bounds_kernel(const int* __restrict__ rowstart,
                              int* __restrict__ B, int* __restrict__ Sb)
{
  if (threadIdx.x != 0 || blockIdx.x != 0) return;
  B[0] = 0;    Sb[0] = 0;
  B[NC] = E_N; Sb[NC] = S_N;
  for (int c = 1; c < NC; ++c) {
    const int target = c * CH;
    int lo = 0, hi = S_N;
    while (lo < hi) {
      const int mid = (lo + hi) >> 1;
      if (rowstart[mid] >= target) hi = mid; else lo = mid + 1;
    }
    Sb[c] = lo;
    B[c] = rowstart[lo];
  }
}

// scatter into sorted order; hist holds running tickets (= rowstart copy)
__global__ __launch_bounds__(256) void scatter_kernel(
    const int* __restrict__ src32, const int* __restrict__ tgt32,
    int* __restrict__ hist, int* __restrict__ perm_e, int* __restrict__ tgt_s)
{
  const int e = blockIdx.x * 256 + threadIdx.x;
  if (e >= E_N) return;
  const int pos = atomicAdd(&hist[src32[e]], 1);
  perm_e[pos] = e;
  tgt_s[pos] = tgt32[e];
}

// ---------------------------------------------------------------------------
// GEMM1 (f32): out[r] = leaky(concat(x_t[tgt_s[B0+r]], ea[perm_e[B0+r]]) @ W^T + b)
// for r in [0, M) where M = B[c+1]-B[c]. Rows >= M compute garbage, stores masked.
// ---------------------------------------------------------------------------
__global__ __launch_bounds__(256) void gemm1_f32_kernel(
    const float* __restrict__ x_t, const float* __restrict__ ea,
    const int* __restrict__ tgt_s, const int* __restrict__ perm_e,
    const float* __restrict__ W, const float* __restrict__ bias,
    float* __restrict__ out, const int* __restrict__ bnds, int c)
{
  __shared__ float As[16][68];
  __shared__ float Bs[16][68];
  __shared__ int s_tgt[64];
  __shared__ int s_ei[64];
  const int B0 = bnds[c];
  const int M  = bnds[c + 1] - B0;
  const int t = threadIdx.x;
  const int by = blockIdx.x, bx = blockIdx.y;
  const int row0 = by * 64;
  if (t < 64) {
    const int r = row0 + t;
    int tg = 0, ei = 0;
    if (r < M) { tg = tgt_s[B0 + r]; ei = perm_e[B0 + r]; }
    s_tgt[t] = tg;
    s_ei[t] = ei;
  }
  __syncthreads();
  const int lr  = t >> 2;
  const int lk4 = (t & 3) * 4;
  const int grow = s_tgt[lr];
  const int eirow = s_ei[lr];
  const int wrow = bx * 64 + lr;
  const int tx = t & 15, ty = t >> 4;
  float acc[4][4] = {};
  for (int kt = 0; kt < FM; kt += 16) {
    const int k0 = kt + lk4;
    const float* ap = (k0 < FD) ? (x_t + (size_t)grow * FD + k0)
                                : (ea + (size_t)eirow * FD + (k0 - FD));
    const float4 av = *(const float4*)ap;
    As[lk4 + 0][lr] = av.x; As[lk4 + 1][lr] = av.y;
    As[lk4 + 2][lr] = av.z; As[lk4 + 3][lr] = av.w;
    const float4 wv = *(const float4*)(W + (size_t)wrow * FM + k0);
    Bs[lk4 + 0][lr] = wv.x; Bs[lk4 + 1][lr] = wv.y;
    Bs[lk4 + 2][lr] = wv.z; Bs[lk4 + 3][lr] = wv.w;
    __syncthreads();
#pragma unroll
    for (int kk = 0; kk < 16; ++kk) {
      float a[4], b[4];
#pragma unroll
      for (int i = 0; i < 4; ++i) a[i] = As[kk][ty * 4 + i];
#pragma unroll
      for (int j = 0; j < 4; ++j) b[j] = Bs[kk][tx * 4 + j];
#pragma unroll
      for (int i = 0; i < 4; ++i)
#pragma unroll
        for (int j = 0; j < 4; ++j) acc[i][j] += a[i] * b[j];
    }
    __syncthreads();
  }
#pragma unroll
  for (int i = 0; i < 4; ++i) {
    const int r = row0 + ty * 4 + i;
    if (r < M) {
#pragma unroll
      for (int j = 0; j < 4; ++j) {
        const int col = bx * 64 + tx * 4 + j;
        float v = acc[i][j] + bias[col];
        v = v > 0.0f ? v : 0.1f * v;
        out[(size_t)r * FM + col] = v;
      }
    }
  }
}

// ---------------------------------------------------------------------------
// Generic f32 GEMM: out[M,N] = act( A[M,K] @ W[N,K]^T + bias[N] )
// ---------------------------------------------------------------------------
template <bool LEAKY>
__global__ __launch_bounds__(256) void gemm_f32_kernel(
    const float* __restrict__ A, const float* __restrict__ W,
    const float* __restrict__ bias, float* __restrict__ out,
    int M, int N, int K)
{
  __shared__ float As[16][68];
  __shared__ float Bs[16][68];
  const int t = threadIdx.x;
  const int by = blockIdx.x, bx = blockIdx.y;
  const int row0 = by * 64;
  const int lr  = t >> 2;
  const int lk4 = (t & 3) * 4;
  const int arow = row0 + lr;
  const int wrow = bx * 64 + lr;
  const int tx = t & 15, ty = t >> 4;
  float acc[4][4] = {};
  for (int kt = 0; kt < K; kt += 16) {
    const int k0 = kt + lk4;
    if (arow < M) {
      const float4 av = *(const float4*)(A + (size_t)arow * K + k0);
      As[lk4 + 0][lr] = av.x; As[lk4 + 1][lr] = av.y;
      As[lk4 + 2][lr] = av.z; As[lk4 + 3][lr] = av.w;
    } else {
      As[lk4 + 0][lr] = 0.f; As[lk4 + 1][lr] = 0.f;
      As[lk4 + 2][lr] = 0.f; As[lk4 + 3][lr] = 0.f;
    }
    const float4 wv = *(const float4*)(W + (size_t)wrow * K + k0);
    Bs[lk4 + 0][lr] = wv.x; Bs[lk4 + 1][lr] = wv.y;
    Bs[lk4 + 2][lr] = wv.z; Bs[lk4 + 3][lr] = wv.w;
    __syncthreads();
#pragma unroll
    for (int kk = 0; kk < 16; ++kk) {
      float a[4], b[4];
#pragma unroll
      for (int i = 0; i < 4; ++i) a[i] = As[kk][ty * 4 + i];
#pragma unroll
      for (int j = 0; j < 4; ++j) b[j] = Bs[kk][tx * 4 + j];
#pragma unroll
      for (int i = 0; i < 4; ++i)
#pragma unroll
        for (int j = 0; j < 4; ++j) acc[i][j] += a[i] * b[j];
    }
    __syncthreads();
  }
#pragma unroll
  for (int i = 0; i < 4; ++i) {
    const int r = row0 + ty * 4 + i;
    if (r < M) {
#pragma unroll
      for (int j = 0; j < 4; ++j) {
        const int col = bx * 64 + tx * 4 + j;
        float v = acc[i][j] + bias[col];
        if (LEAKY) v = v > 0.0f ? v : 0.1f * v;
        out[(size_t)r * N + col] = v;
      }
    }
  }
}

// ---------------------------------------------------------------------------
// Exact per-source stats (reference arithmetic, two passes over the group's
// messages, no atomics). One block per source (grid-stride over chunk's
// sources); thread = feature. Writes mean/std/skew/kurt into h.
// h layout: [0:128)=x_s, [128:384)=mean, [384:640)=std, [640:896)=skew,
// [896:1152)=kurt, [1152:1280)=u.
// ---------------------------------------------------------------------------
__global__ __launch_bounds__(256) void stats_kernel(
    const float* __restrict__ msgc, const int* __restrict__ rowstart,
    const int* __restrict__ bnds, const int* __restrict__ sbnds, int c,
    float* __restrict__ h)
{
  const int B0 = bnds[c];
  const int s_lo = sbnds[c], s_hi = sbnds[c + 1];
  const int f = threadIdx.x;
  for (int s = s_lo + blockIdx.x; s < s_hi; s += gridDim.x) {
    const int r0 = rowstart[s] - B0;
    const int r1 = rowstart[s + 1] - B0;
    const int count = r1 - r0;
    float sum = 0.f, sum2 = 0.f;
    for (int r = r0; r < r1; ++r) {
      const float v = msgc[(size_t)r * FM + f];
      sum += v; sum2 += v * v;
    }
    const float denom = fmaxf((float)count, 1.0f);
    const float mean = sum / denom;
    const float m2   = sum2 / denom;
    float var = m2 - mean * mean;
    var = var > 0.0f ? var : 0.01f * var;
    float sd3 = 0.f, sd4 = 0.f;
    for (int r = r0; r < r1; ++r) {
      const float d = msgc[(size_t)r * FM + f] - mean;
      const float d3 = d * d * d;
      sd3 += d3; sd4 += d3 * d;
    }
    float skew = 0.0f, kurt = 0.0f;
    const float v1e = var + 1e-6f;
    if (v1e > 0.0f) {
      const float stdv = sqrtf(v1e);
      const float st3  = stdv * stdv * stdv;
      skew = (sd3 / denom) / st3;
      kurt = (sd4 / denom) / (st3 * stdv);
    }
    const float var2 = n2n(var);
    const float std2 = sqrtf(fmaxf(var2 + 1e-6f, 0.0f));
    float* base = h + (size_t)s * FM2;
    base[128 + f] = n2n(mean);
    base[384 + f] = std2;
    base[640 + f] = n2n(skew);
    base[896 + f] = n2n(kurt);
  }
}

__global__ __launch_bounds__(256) void build_h_xu_kernel(
    const float* __restrict__ x_s, const float* __restrict__ u,
    float* __restrict__ h)
{
  const int i = blockIdx.x * 256 + threadIdx.x;   // S*FD
  const int s = i >> 7, f = i & 127;
  float* base = h + (size_t)s * FM2;
  base[f] = x_s[i];
  base[1152 + f] = u[f];
}

// BatchNorm
__global__ __launch_bounds__(256) void bn_sum_kernel(
    const float* __restrict__ y, float* __restrict__ bn)
{
  __shared__ float ls[256], lq[256];
  const int t = threadIdx.x;
  const int col = t & 127, half = t >> 7;
  const int rend = min(S_N, (int)blockIdx.x * 256 + 256);
  float sm = 0.f, sq = 0.f;
  for (int r = blockIdx.x * 256 + half; r < rend; r += 2) {
    const float v = y[(size_t)r * FD + col];
    sm += v; sq += v * v;
  }
  ls[t] = sm; lq[t] = sq;
  __syncthreads();
  if (t < 128) {
    atomicAdd(&bn[col],       ls[t] + ls[t + 128]);
    atomicAdd(&bn[128 + col], lq[t] + lq[t + 128]);
  }
}

__global__ __launch_bounds__(256) void bn_norm_kernel(
    const float* __restrict__ y, const float* __restrict__ bn,
    const float* __restrict__ gamma, const float* __restrict__ beta,
    float* __restrict__ out)
{
  const int i = blockIdx.x * 256 + threadIdx.x;   // S*FD
  const int f = i & 127;
  const float mu  = bn[f] * (1.0f / S_N);
  const float var = bn[128 + f] * (1.0f / S_N) - mu * mu;
  const float inv = 1.0f / sqrtf(var + 1e-5f);
  out[i] = (y[i] - mu) * inv * gamma[f] + beta[f];
}

// ---------------------------------------------------------------------------
// Workspace layout, total ~423.5 MB (proven-safe extent < 481 MB):
//   OFF_H    = 0             h f32 [S,1280] (fully written, no zeroing needed)
//   OFF_RS   = 256,000,000   rowstart int [S+1]
//   OFF_TK   = 256,200,192   hist/ticket int [S]      (zeroed)
//   OFF_BN   = 256,400,192   bn f32 [256]             (zeroed)
//   OFF_FLG  = 256,401,216   flags int [2]
//   OFF_B    = 256,401,280   B int[11] + Sb int[11]
//   OFF_Y    = 256,401,536   y f32 [S,128]
//   OFF_G    = 282,001,536   g chunk f32 [RCH,1280]
//   OFF_MSGC = 333,201,536   msg chunk f32 [CH_MAX,256]
//   OFF_H1C  = 375,144,576   h1 chunk f32 [CH_MAX,256]
//   OFF_SRC  = 417,087,616   src32 int [E]
//   OFF_TGT  = 418,687,616   tgt32 int [E]
//   OFF_TGTS = 420,287,616   tgt_sorted int [E]
//   OFF_PERM = 421,887,616   perm_e int [E]  (end 423,487,616)
// ---------------------------------------------------------------------------
#define OFF_H    0ull
#define OFF_RS   256000000ull
#define OFF_TK   256200192ull
#define OFF_BN   256400192ull
#define OFF_FLG  256401216ull
#define OFF_B    256401280ull
#define OFF_Y    256401536ull
#define OFF_G    282001536ull
#define OFF_MSGC 333201536ull
#define OFF_H1C  375144576ull
#define OFF_SRC  417087616ull
#define OFF_TGT  418687616ull
#define OFF_TGTS 420287616ull
#define OFF_PERM 421887616ull

extern "C" void kernel_launch(void* const* d_in, const int* in_sizes, int n_in,
                              void* d_out, int out_size, void* d_ws, size_t ws_size,
                              hipStream_t stream)
{
  const float* x_s  = (const float*)d_in[0];
  const float* x_t  = (const float*)d_in[1];
  const float* ea   = (const float*)d_in[2];
  const float* u    = (const float*)d_in[3];
  const float* W1a  = (const float*)d_in[4];
  const float* b1a  = (const float*)d_in[5];
  const float* W1b  = (const float*)d_in[6];
  const float* b1b  = (const float*)d_in[7];
  const float* W2a  = (const float*)d_in[8];
  const float* b2a  = (const float*)d_in[9];
  const float* W2b  = (const float*)d_in[10];
  const float* b2b  = (const float*)d_in[11];
  const float* gam  = (const float*)d_in[12];
  const float* bet  = (const float*)d_in[13];

  char* ws = (char*)d_ws;
  float* h    = (float*)(ws + OFF_H);
  int*   rs   = (int*)(ws + OFF_RS);
  int*   hist = (int*)(ws + OFF_TK);
  float* bn   = (float*)(ws + OFF_BN);
  int*   flags= (int*)(ws + OFF_FLG);
  int*   bnds = (int*)(ws + OFF_B);          // B[0..10]
  int*   sbnds= (int*)(ws + OFF_B + 64);     // Sb[0..10]
  float* y    = (float*)(ws + OFF_Y);
  float* g    = (float*)(ws + OFF_G);
  float* msgc = (float*)(ws + OFF_MSGC);
  float* h1c  = (float*)(ws + OFF_H1C);
  int*   src32= (int*)(ws + OFF_SRC);
  int*   tgt32= (int*)(ws + OFF_TGT);
  int*   tgt_s= (int*)(ws + OFF_TGTS);
  int*   perm = (int*)(ws + OFF_PERM);

  // zero hist + bn (contiguous region), probe dtype, build sorted order
  hipMemsetAsync(ws + OFF_TK, 0, (size_t)(OFF_BN - OFF_TK) + 1024, stream);
  probe_kernel<<<1, 64, 0, stream>>>(d_in[14], flags);
  idx_kernel<<<(E_N + 255) / 256, 256, 0, stream>>>(d_in[14], src32, tgt32, flags, hist);
  scan_kernel<<<1, 256, 0, stream>>>(hist, rs);
  bounds_kernel<<<1, 1, 0, stream>>>(rs, bnds, sbnds);
  scatter_kernel<<<(E_N + 255) / 256, 256, 0, stream>>>(src32, tgt32, hist, perm, tgt_s);

  // ---- single pass: MLP1 per sorted chunk -> exact per-source stats
  for (int c = 0; c < NC; ++c) {
    gemm1_f32_kernel<<<dim3(CH_MAX / 64, FM / 64), 256, 0, stream>>>(
        x_t, ea, tgt_s, perm, W1a, b1a, h1c, bnds, c);
    gemm_f32_kernel<false><<<dim3(CH_MAX / 64, FM / 64), 256, 0, stream>>>(
        h1c, W1b, b1b, msgc, CH_MAX, FM, FM);
    stats_kernel<<<5120, 256, 0, stream>>>(msgc, rs, bnds, sbnds, c, h);
  }
  build_h_xu_kernel<<<(S_N * FD) / 256, 256, 0, stream>>>(x_s, u, h);

  // ---- MLP2, row-chunked: h -> g -> y
  for (int c = 0; c < S_N / RCH; ++c) {
    const size_t r0 = (size_t)c * RCH;
    gemm_f32_kernel<true><<<dim3((RCH + 63) / 64, FM2 / 64), 256, 0, stream>>>(
        h + r0 * FM2, W2a, b2a, g, RCH, FM2, FM2);
    gemm_f32_kernel<false><<<dim3((RCH + 63) / 64, FD / 64), 256, 0, stream>>>(
        g, W2b, b2b, y + r0 * FD, RCH, FD, FM2);
  }

  // ---- BatchNorm -> d_out (f32)
  bn_sum_kernel<<<(S_N + 255) / 256, 256, 0, stream>>>(y, bn);
  bn_norm_kernel<<<(S_N * FD) / 256, 256, 0, stream>>>(y, bn, gam, bet, (float*)d_out);
}

// Round 5
// 2849.143 us; speedup vs baseline: 1.8091x; 1.8091x over previous
//
#include <hip/hip_runtime.h>
#include <hip/hip_bf16.h>

#define S_N 50000
#define E_N 400000
#define FD 128
#define FM 256
#define FM2 1280
#define CH 40000       // nominal chunk edges; boundaries snapped UP to source bounds
#define CH_MAX 40960   // padded chunk capacity (640 * 64)
#define NC 10

typedef __attribute__((ext_vector_type(8))) short short8;
typedef __attribute__((ext_vector_type(4))) float f32x4;

// jnp.nan_to_num
__device__ __forceinline__ float n2n(float x) {
  if (x != x) return 0.0f;
  const float M = 3.402823466e38f;
  if (x > M) return M;
  if (x < -M) return -M;
  return x;
}

// ---------------------------------------------------------------------------
// Probe index dtype. flags[1] = 1 if int64 edge_index.
// ---------------------------------------------------------------------------
__global__ void probe_kernel(const void* __restrict__ eidx_raw, int* __restrict__ flags)
{
  if (threadIdx.x != 0 || blockIdx.x != 0) return;
  const long long* e64 = (const long long*)eidx_raw;
  int ok64 = 1;
  for (int i = 0; i < 64; ++i) {
    long long v = e64[i];
    if (v < 0 || v >= S_N) { ok64 = 0; break; }
  }
  flags[1] = ok64;
}

// idx normalize + histogram into hist[] (pre-zeroed)
__global__ __launch_bounds__(256) void idx_kernel(
    const void* __restrict__ eidx, int* __restrict__ src32,
    int* __restrict__ tgt32, const int* __restrict__ flags,
    int* __restrict__ hist)
{
  const int e = blockIdx.x * 256 + threadIdx.x;
  if (e >= E_N) return;
  int s, t;
  if (flags[1]) {
    const long long* p = (const long long*)eidx;
    s = (int)p[e];
    t = (int)p[E_N + e];
  } else {
    const int* p = (const int*)eidx;
    s = p[e];
    t = p[E_N + e];
  }
  src32[e] = s;
  tgt32[e] = t;
  atomicAdd(&hist[s], 1);
}

// single-block exclusive scan: hist[s] (counts) -> rowstart[s]; hist becomes
// a working copy of rowstart (consumed by scatter's tickets).
__global__ __launch_bounds__(256) void scan_kernel(
    int* __restrict__ hist, int* __restrict__ rowstart)
{
  __shared__ int tmp[256];
  __shared__ int sbase;
  const int t = threadIdx.x;
  if (t == 0) sbase = 0;
  __syncthreads();
  for (int tile = 0; tile < S_N; tile += 256) {
    const int idx = tile + t;
    const int v = (idx < S_N) ? hist[idx] : 0;
    tmp[t] = v;
    __syncthreads();
    for (int off = 1; off < 256; off <<= 1) {
      int x = 0;
      if (t >= off) x = tmp[t - off];
      __syncthreads();
      tmp[t] += x;
      __syncthreads();
    }
    const int excl = sbase + tmp[t] - v;
    if (idx < S_N) { rowstart[idx] = excl; hist[idx] = excl; }
    __syncthreads();
    if (t == 0) sbase += tmp[255];
    __syncthreads();
  }
  if (t == 0) rowstart[S_N] = sbase;   // == E_N
}

// chunk boundaries snapped to source boundaries
__global__ void bounds_kernel(const int* __restrict__ rowstart,
                              int* __restrict__ B, int* __restrict__ Sb)
{
  if (threadIdx.x != 0 || blockIdx.x != 0) return;
  B[0] = 0;    Sb[0] = 0;
  B[NC] = E_N; Sb[NC] = S_N;
  for (int c = 1; c < NC; ++c) {
    const int target = c * CH;
    int lo = 0, hi = S_N;
    while (lo < hi) {
      const int mid = (lo + hi) >> 1;
      if (rowstart[mid] >= target) hi = mid; else lo = mid + 1;
    }
    Sb[c] = lo;
    B[c] = rowstart[lo];
  }
}

// scatter into sorted order; hist holds running tickets (= rowstart copy)
__global__ __launch_bounds__(256) void scatter_kernel(
    const int* __restrict__ src32, const int* __restrict__ tgt32,
    int* __restrict__ hist, int* __restrict__ perm_e, int* __restrict__ tgt_s)
{
  const int e = blockIdx.x * 256 + threadIdx.x;
  if (e >= E_N) return;
  const int pos = atomicAdd(&hist[src32[e]], 1);
  perm_e[pos] = e;
  tgt_s[pos] = tgt32[e];
}

// f32 -> bf16 cast
__global__ __launch_bounds__(256) void cast_bf16_kernel(
    const float* __restrict__ in, __hip_bfloat16* __restrict__ out, int n)
{
  const int i = blockIdx.x * 256 + threadIdx.x;
  if (i < n) out[i] = __float2bfloat16(in[i]);
}

// ---------------------------------------------------------------------------
// GEMM1 (f32): out[r] = leaky(concat(x_t[tgt_s[B0+r]], ea[perm_e[B0+r]]) @ W^T + b)
// ---------------------------------------------------------------------------
__global__ __launch_bounds__(256) void gemm1_f32_kernel(
    const float* __restrict__ x_t, const float* __restrict__ ea,
    const int* __restrict__ tgt_s, const int* __restrict__ perm_e,
    const float* __restrict__ W, const float* __restrict__ bias,
    float* __restrict__ out, const int* __restrict__ bnds, int c)
{
  __shared__ float As[16][68];
  __shared__ float Bs[16][68];
  __shared__ int s_tgt[64];
  __shared__ int s_ei[64];
  const int B0 = bnds[c];
  const int M  = bnds[c + 1] - B0;
  const int t = threadIdx.x;
  const int by = blockIdx.x, bx = blockIdx.y;
  const int row0 = by * 64;
  if (t < 64) {
    const int r = row0 + t;
    int tg = 0, ei = 0;
    if (r < M) { tg = tgt_s[B0 + r]; ei = perm_e[B0 + r]; }
    s_tgt[t] = tg;
    s_ei[t] = ei;
  }
  __syncthreads();
  const int lr  = t >> 2;
  const int lk4 = (t & 3) * 4;
  const int grow = s_tgt[lr];
  const int eirow = s_ei[lr];
  const int wrow = bx * 64 + lr;
  const int tx = t & 15, ty = t >> 4;
  float acc[4][4] = {};
  for (int kt = 0; kt < FM; kt += 16) {
    const int k0 = kt + lk4;
    const float* ap = (k0 < FD) ? (x_t + (size_t)grow * FD + k0)
                                : (ea + (size_t)eirow * FD + (k0 - FD));
    const float4 av = *(const float4*)ap;
    As[lk4 + 0][lr] = av.x; As[lk4 + 1][lr] = av.y;
    As[lk4 + 2][lr] = av.z; As[lk4 + 3][lr] = av.w;
    const float4 wv = *(const float4*)(W + (size_t)wrow * FM + k0);
    Bs[lk4 + 0][lr] = wv.x; Bs[lk4 + 1][lr] = wv.y;
    Bs[lk4 + 2][lr] = wv.z; Bs[lk4 + 3][lr] = wv.w;
    __syncthreads();
#pragma unroll
    for (int kk = 0; kk < 16; ++kk) {
      float a[4], b[4];
#pragma unroll
      for (int i = 0; i < 4; ++i) a[i] = As[kk][ty * 4 + i];
#pragma unroll
      for (int j = 0; j < 4; ++j) b[j] = Bs[kk][tx * 4 + j];
#pragma unroll
      for (int i = 0; i < 4; ++i)
#pragma unroll
        for (int j = 0; j < 4; ++j) acc[i][j] += a[i] * b[j];
    }
    __syncthreads();
  }
#pragma unroll
  for (int i = 0; i < 4; ++i) {
    const int r = row0 + ty * 4 + i;
    if (r < M) {
#pragma unroll
      for (int j = 0; j < 4; ++j) {
        const int col = bx * 64 + tx * 4 + j;
        float v = acc[i][j] + bias[col];
        v = v > 0.0f ? v : 0.1f * v;
        out[(size_t)r * FM + col] = v;
      }
    }
  }
}

// ---------------------------------------------------------------------------
// Generic f32 GEMM (kept for MLP1b): out[M,N] = A[M,K] @ W[N,K]^T + bias[N]
// ---------------------------------------------------------------------------
template <bool LEAKY>
__global__ __launch_bounds__(256) void gemm_f32_kernel(
    const float* __restrict__ A, const float* __restrict__ W,
    const float* __restrict__ bias, float* __restrict__ out,
    int M, int N, int K)
{
  __shared__ float As[16][68];
  __shared__ float Bs[16][68];
  const int t = threadIdx.x;
  const int by = blockIdx.x, bx = blockIdx.y;
  const int row0 = by * 64;
  const int lr  = t >> 2;
  const int lk4 = (t & 3) * 4;
  const int arow = row0 + lr;
  const int wrow = bx * 64 + lr;
  const int tx = t & 15, ty = t >> 4;
  float acc[4][4] = {};
  for (int kt = 0; kt < K; kt += 16) {
    const int k0 = kt + lk4;
    if (arow < M) {
      const float4 av = *(const float4*)(A + (size_t)arow * K + k0);
      As[lk4 + 0][lr] = av.x; As[lk4 + 1][lr] = av.y;
      As[lk4 + 2][lr] = av.z; As[lk4 + 3][lr] = av.w;
    } else {
      As[lk4 + 0][lr] = 0.f; As[lk4 + 1][lr] = 0.f;
      As[lk4 + 2][lr] = 0.f; As[lk4 + 3][lr] = 0.f;
    }
    const float4 wv = *(const float4*)(W + (size_t)wrow * K + k0);
    Bs[lk4 + 0][lr] = wv.x; Bs[lk4 + 1][lr] = wv.y;
    Bs[lk4 + 2][lr] = wv.z; Bs[lk4 + 3][lr] = wv.w;
    __syncthreads();
#pragma unroll
    for (int kk = 0; kk < 16; ++kk) {
      float a[4], b[4];
#pragma unroll
      for (int i = 0; i < 4; ++i) a[i] = As[kk][ty * 4 + i];
#pragma unroll
      for (int j = 0; j < 4; ++j) b[j] = Bs[kk][tx * 4 + j];
#pragma unroll
      for (int i = 0; i < 4; ++i)
#pragma unroll
        for (int j = 0; j < 4; ++j) acc[i][j] += a[i] * b[j];
    }
    __syncthreads();
  }
#pragma unroll
  for (int i = 0; i < 4; ++i) {
    const int r = row0 + ty * 4 + i;
    if (r < M) {
#pragma unroll
      for (int j = 0; j < 4; ++j) {
        const int col = bx * 64 + tx * 4 + j;
        float v = acc[i][j] + bias[col];
        if (LEAKY) v = v > 0.0f ? v : 0.1f * v;
        out[(size_t)r * N + col] = v;
      }
    }
  }
}

// ---------------------------------------------------------------------------
// MFMA bf16 GEMM: out[M,N] = act( A[M,K]bf16 @ W[N,K]bf16^T + bias[N] )
// 128x128 tile, 4 waves (2x2), 16x16x32 MFMA, 4x4 frags/wave.
// A and B frags both loaded K-contiguous from LDS -> any internal k-slot
// permutation cancels in the dot product. C/D: col=lane&15, row=(lane>>4)*4+r.
// LDS rows padded to 40 shorts (80 B): 16B-aligned b128, <=2-way bank conflict.
// N must be a multiple of 128; rows clamped/masked for M.
// ---------------------------------------------------------------------------
template <bool LEAKY, bool OUT_BF16>
__global__ __launch_bounds__(256) void gemm_mfma_kernel(
    const ushort* __restrict__ A, const ushort* __restrict__ W,
    const float* __restrict__ bias, void* __restrict__ out,
    int M, int N, int K)
{
  __shared__ __align__(16) ushort lA[128][40];
  __shared__ __align__(16) ushort lB[128][40];
  const int t = threadIdx.x;
  const int row0 = blockIdx.x * 128;
  const int col0 = blockIdx.y * 128;
  const int wid = t >> 6, lane = t & 63;
  const int wm = wid >> 1, wn = wid & 1;
  const int lr = lane & 15, lg = lane >> 4;

  const int ra = t >> 2;             // staging row (0..63), +64 for second
  const int sa = (t & 3) * 8;        // staging k-seg (bf16 units)
  const int garow0 = min(row0 + ra, M - 1);
  const int garow1 = min(row0 + ra + 64, M - 1);
  const int gbrow0 = col0 + ra;      // N multiple of 128: always in-bounds
  const int gbrow1 = col0 + ra + 64;

  f32x4 acc[4][4] = {};

  for (int kt = 0; kt < K; kt += 32) {
    *(float4*)&lA[ra][sa]      = *(const float4*)&A[(size_t)garow0 * K + kt + sa];
    *(float4*)&lA[ra + 64][sa] = *(const float4*)&A[(size_t)garow1 * K + kt + sa];
    *(float4*)&lB[ra][sa]      = *(const float4*)&W[(size_t)gbrow0 * K + kt + sa];
    *(float4*)&lB[ra + 64][sa] = *(const float4*)&W[(size_t)gbrow1 * K + kt + sa];
    __syncthreads();
    short8 af[4], bf[4];
#pragma unroll
    for (int i = 0; i < 4; ++i)
      af[i] = *(const short8*)&lA[wm * 64 + i * 16 + lr][lg * 8];
#pragma unroll
    for (int j = 0; j < 4; ++j)
      bf[j] = *(const short8*)&lB[wn * 64 + j * 16 + lr][lg * 8];
#pragma unroll
    for (int i = 0; i < 4; ++i)
#pragma unroll
      for (int j = 0; j < 4; ++j)
        acc[i][j] = __builtin_amdgcn_mfma_f32_16x16x32_bf16(af[i], bf[j], acc[i][j], 0, 0, 0);
    __syncthreads();
  }

#pragma unroll
  for (int i = 0; i < 4; ++i) {
#pragma unroll
    for (int j = 0; j < 4; ++j) {
      const int col = col0 + wn * 64 + j * 16 + lr;
#pragma unroll
      for (int r = 0; r < 4; ++r) {
        const int row = row0 + wm * 64 + i * 16 + lg * 4 + r;
        if (row < M) {
          float v = acc[i][j][r] + bias[col];
          if (LEAKY) v = v > 0.0f ? v : 0.1f * v;
          if (OUT_BF16)
            ((__hip_bfloat16*)out)[(size_t)row * N + col] = __float2bfloat16(v);
          else
            ((float*)out)[(size_t)row * N + col] = v;
        }
      }
    }
  }
}

// ---------------------------------------------------------------------------
// Exact per-source stats (reference arithmetic in f32), results rounded ONCE
// to bf16 into h_bf [S,1280]: [0:128)=x_s, [128:384)=mean, [384:640)=std,
// [640:896)=skew, [896:1152)=kurt, [1152:1280)=u.
// ---------------------------------------------------------------------------
__global__ __launch_bounds__(256) void stats_kernel(
    const float* __restrict__ msgc, const int* __restrict__ rowstart,
    const int* __restrict__ bnds, const int* __restrict__ sbnds, int c,
    __hip_bfloat16* __restrict__ h)
{
  const int B0 = bnds[c];
  const int s_lo = sbnds[c], s_hi = sbnds[c + 1];
  const int f = threadIdx.x;
  for (int s = s_lo + blockIdx.x; s < s_hi; s += gridDim.x) {
    const int r0 = rowstart[s] - B0;
    const int r1 = rowstart[s + 1] - B0;
    const int count = r1 - r0;
    float sum = 0.f, sum2 = 0.f;
    for (int r = r0; r < r1; ++r) {
      const float v = msgc[(size_t)r * FM + f];
      sum += v; sum2 += v * v;
    }
    const float denom = fmaxf((float)count, 1.0f);
    const float mean = sum / denom;
    const float m2   = sum2 / denom;
    float var = m2 - mean * mean;
    var = var > 0.0f ? var : 0.01f * var;
    float sd3 = 0.f, sd4 = 0.f;
    for (int r = r0; r < r1; ++r) {
      const float d = msgc[(size_t)r * FM + f] - mean;
      const float d3 = d * d * d;
      sd3 += d3; sd4 += d3 * d;
    }
    float skew = 0.0f, kurt = 0.0f;
    const float v1e = var + 1e-6f;
    if (v1e > 0.0f) {
      const float stdv = sqrtf(v1e);
      const float st3  = stdv * stdv * stdv;
      skew = (sd3 / denom) / st3;
      kurt = (sd4 / denom) / (st3 * stdv);
    }
    const float var2 = n2n(var);
    const float std2 = sqrtf(fmaxf(var2 + 1e-6f, 0.0f));
    __hip_bfloat16* base = h + (size_t)s * FM2;
    base[128 + f] = __float2bfloat16(n2n(mean));
    base[384 + f] = __float2bfloat16(std2);
    base[640 + f] = __float2bfloat16(n2n(skew));
    base[896 + f] = __float2bfloat16(n2n(kurt));
  }
}

__global__ __launch_bounds__(256) void build_h_xu_kernel(
    const float* __restrict__ x_s, const float* __restrict__ u,
    __hip_bfloat16* __restrict__ h)
{
  const int i = blockIdx.x * 256 + threadIdx.x;   // S*FD
  const int s = i >> 7, f = i & 127;
  __hip_bfloat16* base = h + (size_t)s * FM2;
  base[f] = __float2bfloat16(x_s[i]);
  base[1152 + f] = __float2bfloat16(u[f]);
}

// BatchNorm
__global__ __launch_bounds__(256) void bn_sum_kernel(
    const float* __restrict__ y, float* __restrict__ bn)
{
  __shared__ float ls[256], lq[256];
  const int t = threadIdx.x;
  const int col = t & 127, half = t >> 7;
  const int rend = min(S_N, (int)blockIdx.x * 256 + 256);
  float sm = 0.f, sq = 0.f;
  for (int r = blockIdx.x * 256 + half; r < rend; r += 2) {
    const float v = y[(size_t)r * FD + col];
    sm += v; sq += v * v;
  }
  ls[t] = sm; lq[t] = sq;
  __syncthreads();
  if (t < 128) {
    atomicAdd(&bn[col],       ls[t] + ls[t + 128]);
    atomicAdd(&bn[128 + col], lq[t] + lq[t + 128]);
  }
}

__global__ __launch_bounds__(256) void bn_norm_kernel(
    const float* __restrict__ y, const float* __restrict__ bn,
    const float* __restrict__ gamma, const float* __restrict__ beta,
    float* __restrict__ out)
{
  const int i = blockIdx.x * 256 + threadIdx.x;   // S*FD
  const int f = i & 127;
  const float mu  = bn[f] * (1.0f / S_N);
  const float var = bn[128 + f] * (1.0f / S_N) - mu * mu;
  const float inv = 1.0f / sqrtf(var + 1e-5f);
  out[i] = (y[i] - mu) * inv * gamma[f] + beta[f];
}

// ---------------------------------------------------------------------------
// Workspace layout, total ~376 MB (proven-safe extent < 481 MB):
//   OFF_HBF  = 0             h bf16 [S,1280]  (128,000,000)
//   OFF_GBF  = 128,000,000   g bf16 [S,1280]  (128,000,000)
//   OFF_Y    = 256,000,000   y f32 [S,128]    (25,600,000)
//   OFF_MSGC = 281,600,000   msg chunk f32 [CH_MAX,256] (41,943,040)
//   OFF_H1C  = 323,543,040   h1 chunk f32 [CH_MAX,256]  (41,943,040)
//   OFF_W2A  = 365,486,080   W2a bf16 [1280,1280] (3,276,800)
//   OFF_W2B  = 368,762,880   W2b bf16 [128,1280]  (327,680)
//   OFF_RS   = 369,090,560   rowstart int [S+1]
//   OFF_TK   = 369,290,752   hist/ticket int [S]  (zeroed)
//   OFF_BN   = 369,490,752   bn f32 [256]         (zeroed)
//   OFF_FLG  = 369,491,776   flags int [2]
//   OFF_B    = 369,491,840   B int[11] + Sb int[11]
//   OFF_SRC  = 369,492,096   src32 int [E]
//   OFF_TGT  = 371,092,096   tgt32 int [E]
//   OFF_TGTS = 372,692,096   tgt_sorted int [E]
//   OFF_PERM = 374,292,096   perm_e int [E]   (end 375,892,096)
// ---------------------------------------------------------------------------
#define OFF_HBF  0ull
#define OFF_GBF  128000000ull
#define OFF_Y    256000000ull
#define OFF_MSGC 281600000ull
#define OFF_H1C  323543040ull
#define OFF_W2A  365486080ull
#define OFF_W2B  368762880ull
#define OFF_RS   369090560ull
#define OFF_TK   369290752ull
#define OFF_BN   369490752ull
#define OFF_FLG  369491776ull
#define OFF_B    369491840ull
#define OFF_SRC  369492096ull
#define OFF_TGT  371092096ull
#define OFF_TGTS 372692096ull
#define OFF_PERM 374292096ull

extern "C" void kernel_launch(void* const* d_in, const int* in_sizes, int n_in,
                              void* d_out, int out_size, void* d_ws, size_t ws_size,
                              hipStream_t stream)
{
  const float* x_s  = (const float*)d_in[0];
  const float* x_t  = (const float*)d_in[1];
  const float* ea   = (const float*)d_in[2];
  const float* u    = (const float*)d_in[3];
  const float* W1a  = (const float*)d_in[4];
  const float* b1a  = (const float*)d_in[5];
  const float* W1b  = (const float*)d_in[6];
  const float* b1b  = (const float*)d_in[7];
  const float* W2a  = (const float*)d_in[8];
  const float* b2a  = (const float*)d_in[9];
  const float* W2b  = (const float*)d_in[10];
  const float* b2b  = (const float*)d_in[11];
  const float* gam  = (const float*)d_in[12];
  const float* bet  = (const float*)d_in[13];

  char* ws = (char*)d_ws;
  __hip_bfloat16* h_bf = (__hip_bfloat16*)(ws + OFF_HBF);
  __hip_bfloat16* g_bf = (__hip_bfloat16*)(ws + OFF_GBF);
  float* y    = (float*)(ws + OFF_Y);
  float* msgc = (float*)(ws + OFF_MSGC);
  float* h1c  = (float*)(ws + OFF_H1C);
  __hip_bfloat16* w2a_bf = (__hip_bfloat16*)(ws + OFF_W2A);
  __hip_bfloat16* w2b_bf = (__hip_bfloat16*)(ws + OFF_W2B);
  int*   rs   = (int*)(ws + OFF_RS);
  int*   hist = (int*)(ws + OFF_TK);
  float* bn   = (float*)(ws + OFF_BN);
  int*   flags= (int*)(ws + OFF_FLG);
  int*   bnds = (int*)(ws + OFF_B);          // B[0..10]
  int*   sbnds= (int*)(ws + OFF_B + 64);     // Sb[0..10]
  int*   src32= (int*)(ws + OFF_SRC);
  int*   tgt32= (int*)(ws + OFF_TGT);
  int*   tgt_s= (int*)(ws + OFF_TGTS);
  int*   perm = (int*)(ws + OFF_PERM);

  // zero hist + bn (contiguous); probe dtype; build sorted order
  hipMemsetAsync(ws + OFF_TK, 0, 201024, stream);
  probe_kernel<<<1, 64, 0, stream>>>(d_in[14], flags);
  idx_kernel<<<(E_N + 255) / 256, 256, 0, stream>>>(d_in[14], src32, tgt32, flags, hist);
  scan_kernel<<<1, 256, 0, stream>>>(hist, rs);
  bounds_kernel<<<1, 1, 0, stream>>>(rs, bnds, sbnds);
  scatter_kernel<<<(E_N + 255) / 256, 256, 0, stream>>>(src32, tgt32, hist, perm, tgt_s);

  // cast MLP2 weights to bf16
  cast_bf16_kernel<<<(FM2 * FM2 + 255) / 256, 256, 0, stream>>>(W2a, w2a_bf, FM2 * FM2);
  cast_bf16_kernel<<<(FD * FM2 + 255) / 256, 256, 0, stream>>>(W2b, w2b_bf, FD * FM2);

  // ---- single pass: MLP1 (f32) per sorted chunk -> exact stats -> h_bf
  for (int c = 0; c < NC; ++c) {
    gemm1_f32_kernel<<<dim3(CH_MAX / 64, FM / 64), 256, 0, stream>>>(
        x_t, ea, tgt_s, perm, W1a, b1a, h1c, bnds, c);
    gemm_f32_kernel<false><<<dim3(CH_MAX / 64, FM / 64), 256, 0, stream>>>(
        h1c, W1b, b1b, msgc, CH_MAX, FM, FM);
    stats_kernel<<<5120, 256, 0, stream>>>(msgc, rs, bnds, sbnds, c, h_bf);
  }
  build_h_xu_kernel<<<(S_N * FD) / 256, 256, 0, stream>>>(x_s, u, h_bf);

  // ---- MLP2 (bf16 MFMA), full S in one shot: h_bf -> g_bf -> y
  gemm_mfma_kernel<true, true><<<dim3((S_N + 127) / 128, FM2 / 128), 256, 0, stream>>>(
      (const ushort*)h_bf, (const ushort*)w2a_bf, b2a, g_bf, S_N, FM2, FM2);
  gemm_mfma_kernel<false, false><<<dim3((S_N + 127) / 128, FD / 128), 256, 0, stream>>>(
      (const ushort*)g_bf, (const ushort*)w2b_bf, b2b, y, S_N, FD, FM2);

  // ---- BatchNorm -> d_out (f32)
  bn_sum_kernel<<<(S_N + 255) / 256, 256, 0, stream>>>(y, bn);
  bn_norm_kernel<<<(S_N * FD) / 256, 256, 0, stream>>>(y, bn, gam, bet, (float*)d_out);
}